// Round 7
// baseline (583.915 us; speedup 1.0000x reference)
//
#include <hip/hip_runtime.h>
#include <hip/hip_bf16.h>

using bf16 = __hip_bfloat16;
typedef __attribute__((ext_vector_type(8))) short short8;
typedef __attribute__((ext_vector_type(4))) short short4v;
typedef __attribute__((ext_vector_type(4))) float floatx4;

#define DEVFN __device__ __forceinline__

DEVFN float bf2f(bf16 v) { return __bfloat162float(v); }
DEVFN bf16 f2bf(float v) { return __float2bfloat16(v); }
DEVFN float us2f(unsigned short u) {
    union { unsigned int i; float f; } c; c.i = ((unsigned int)u) << 16; return c.f;
}
DEVFN unsigned short f2bfbits(float v) {
    union { bf16 h; unsigned short u; } c; c.h = f2bf(v); return c.u;
}
// dtype-dispatched load: isf=1 -> fp32 buffer, isf=0 -> bf16 buffer
DEVFN float loadF(const void* p, size_t i, int isf) {
    return isf ? ((const float*)p)[i] : us2f(((const unsigned short*)p)[i]);
}
// async global->LDS, 16B per lane; lds dest = wave-uniform base + lane*16
DEVFN void gl_lds16(const bf16* g, short* l) {
    __builtin_amdgcn_global_load_lds(
        (const __attribute__((address_space(1))) unsigned int*)g,
        (__attribute__((address_space(3))) unsigned int*)l, 16, 0, 0);
}
// tanh-form GELU, overflow-safe
DEVFN float fast_gelu(float v) {
    float u = v * (0.7978845608028654f + 0.0356774081f * v * v);
    float e = __expf(2.f * u);
    float th = 1.f - 2.f / (e + 1.f);
    return 0.5f * v * (1.f + th);
}

// ---------------------------------------------------------------------------
// Detect input dtype: fp32 N(0,1) -> low halves random -> exp==0xFF hits.
__global__ __launch_bounds__(256) void detect_kernel(const void* x, int* flag)
{
    __shared__ int any;
    if (threadIdx.x == 0) any = 0;
    __syncthreads();
    const unsigned short* p = (const unsigned short*)x;
    int hit = 0;
    for (int i = threadIdx.x; i < 8192; i += 256) {
        if ((p[i] & 0x7F80u) == 0x7F80u) hit = 1;
    }
    if (hit) any = 1;
    __syncthreads();
    if (threadIdx.x == 0) flag[0] = any;
}

__global__ __launch_bounds__(256) void convert_kernel(
    const void* __restrict__ src, bf16* __restrict__ dst, const int* __restrict__ flag, int n)
{
    int isf = *flag;
    int i = blockIdx.x * 256 + threadIdx.x;
    if (i < n) dst[i] = f2bf(loadF(src, i, isf));
}

struct SegTab {
    const void* src[12];
    int off[12];
    int cnt[12];
};
__global__ __launch_bounds__(256) void param_convert_kernel(
    SegTab tab, bf16* __restrict__ dst, const int* __restrict__ flag)
{
    int isf = *flag;
    int s = blockIdx.x;
    const void* src = tab.src[s];
    int off = tab.off[s], cnt = tab.cnt[s];
    for (int i = threadIdx.x; i < cnt; i += 256)
        dst[off + i] = f2bf(loadF(src, i, isf));
}

// ---------------------------------------------------------------------------
// Fused: t[b,n,:] = x[b,:,n] (transpose) then t += LN1(t), all in one pass.
// Block = 16 n-rows x 512 c. LDS tile padded to 516 floats/row (16B-aligned,
// near-conflict-free for both the transpose write and the b128 row reads).
__global__ __launch_bounds__(256) void ln_in_kernel(
    const void* __restrict__ x, float* __restrict__ t,
    const bf16* __restrict__ g, const bf16* __restrict__ bta,
    const int* __restrict__ flag, int NN)
{
    __shared__ float tile[16][516];
    int isf = *flag;
    int b = blockIdx.y;
    int n0 = blockIdx.x * 16;
    int tid = threadIdx.x;
    int nx = tid & 15, cy = tid >> 4;   // 16 c-rows per pass
#pragma unroll
    for (int p = 0; p < 32; p++) {
        int c = p * 16 + cy;
        tile[nx][c] = loadF(x, ((size_t)b * 512 + c) * NN + n0 + nx, isf);
    }
    __syncthreads();
    int w = tid >> 6, lane = tid & 63;
    for (int rr = 0; rr < 4; rr++) {
        int r = w * 4 + rr;
        float4 v0 = *(const float4*)&tile[r][lane * 8];
        float4 v1 = *(const float4*)&tile[r][lane * 8 + 4];
        float vals[8] = {v0.x, v0.y, v0.z, v0.w, v1.x, v1.y, v1.z, v1.w};
        float s = 0.f;
#pragma unroll
        for (int i = 0; i < 8; i++) s += vals[i];
#pragma unroll
        for (int off = 32; off; off >>= 1) s += __shfl_xor(s, off, 64);
        float mu = s * (1.f / 512.f);
        float sq = 0.f;
#pragma unroll
        for (int i = 0; i < 8; i++) { float d = vals[i] - mu; sq += d * d; }
#pragma unroll
        for (int off = 32; off; off >>= 1) sq += __shfl_xor(sq, off, 64);
        float rs = rsqrtf(sq * (1.f / 512.f) + 1e-5f);
        float out[8];
#pragma unroll
        for (int i = 0; i < 8; i++) {
            int c = lane * 8 + i;
            out[i] = vals[i] + (vals[i] - mu) * rs * bf2f(g[c]) + bf2f(bta[c]);
        }
        float* tp = t + ((size_t)b * NN + n0 + r) * 512 + lane * 8;
        *(float4*)tp = make_float4(out[0], out[1], out[2], out[3]);
        *(float4*)(tp + 4) = make_float4(out[4], out[5], out[6], out[7]);
    }
}

// Transpose t (B,N,C) fp32 -> out (B,C,N) in the detected output dtype
__global__ __launch_bounds__(256) void transpose_out_kernel(
    const float* __restrict__ t, void* __restrict__ o, const int* __restrict__ flag,
    int C, int NN)
{
    __shared__ float tile[32][33];
    int isf = *flag;
    int b = blockIdx.z;
    int n0 = blockIdx.x * 32, c0 = blockIdx.y * 32;
    int tx = threadIdx.x, ty = threadIdx.y;
#pragma unroll
    for (int i = 0; i < 4; i++)
        tile[ty + i * 8][tx] = t[((size_t)b * NN + n0 + ty + i * 8) * C + c0 + tx];
    __syncthreads();
#pragma unroll
    for (int i = 0; i < 4; i++) {
        size_t oi = ((size_t)b * C + c0 + ty + i * 8) * NN + n0 + tx;
        float val = tile[tx][ty + i * 8];
        if (isf) ((float*)o)[oi] = val;
        else ((bf16*)o)[oi] = f2bf(val);
    }
}

// Transpose W (K,Nc) -> WT (Nc,K) bf16
__global__ __launch_bounds__(256) void transpose_w_kernel(
    const void* __restrict__ Wm, bf16* __restrict__ WT, const int* __restrict__ flag,
    int K, int Nc)
{
    __shared__ float tile[32][33];
    int isf = *flag;
    int n0 = blockIdx.x * 32, k0 = blockIdx.y * 32;
    int tx = threadIdx.x, ty = threadIdx.y;
#pragma unroll
    for (int i = 0; i < 4; i++)
        tile[ty + i * 8][tx] = loadF(Wm, (size_t)(k0 + ty + i * 8) * Nc + n0 + tx, isf);
    __syncthreads();
#pragma unroll
    for (int i = 0; i < 4; i++)
        WT[(size_t)(n0 + ty + i * 8) * K + k0 + tx] = f2bf(tile[tx][ty + i * 8]);
}

// ---------------------------------------------------------------------------
// LayerNorm over C=512: out = bf16(LN(t)).
__global__ __launch_bounds__(256) void ln_kernel(
    const float* __restrict__ t, const bf16* __restrict__ g, const bf16* __restrict__ bta,
    bf16* __restrict__ outp, int Mrows)
{
    int w = threadIdx.x >> 6, lane = threadIdx.x & 63;
    int row = blockIdx.x * 4 + w;
    if (row >= Mrows) return;
    const float* xr = t + (size_t)row * 512;
    float4 v0 = *(const float4*)(xr + lane * 8);
    float4 v1 = *(const float4*)(xr + lane * 8 + 4);
    float vals[8] = {v0.x, v0.y, v0.z, v0.w, v1.x, v1.y, v1.z, v1.w};
    float s = 0.f;
#pragma unroll
    for (int i = 0; i < 8; i++) s += vals[i];
#pragma unroll
    for (int off = 32; off; off >>= 1) s += __shfl_xor(s, off, 64);
    float mu = s * (1.f / 512.f);
    float sq = 0.f;
#pragma unroll
    for (int i = 0; i < 8; i++) { float d = vals[i] - mu; sq += d * d; }
#pragma unroll
    for (int off = 32; off; off >>= 1) sq += __shfl_xor(sq, off, 64);
    float rs = rsqrtf(sq * (1.f / 512.f) + 1e-5f);
#pragma unroll
    for (int i = 0; i < 8; i++) {
        int c = lane * 8 + i;
        float y = (vals[i] - mu) * rs * bf2f(g[c]) + bf2f(bta[c]);
        outp[(size_t)row * 512 + c] = f2bf(y);
    }
}

// ---------------------------------------------------------------------------
// 64-tile GEMM (kept for small/ragged M): out = epi(A @ WT^T + bias)
template <int MODE>
__global__ __launch_bounds__(256) void gemm64(
    const bf16* __restrict__ A, const bf16* __restrict__ WT,
    const bf16* __restrict__ bias, void* __restrict__ outp,
    int M, int K, int Nc)
{
    __shared__ short As[64 * 32];
    __shared__ short Bs[64 * 32];
    const int tid = threadIdx.x;
    const int m0 = blockIdx.y * 64;
    const int n0 = blockIdx.x * 64;
    const int w = tid >> 6;
    const int lane = tid & 63;
    const int lm = lane & 15;
    const int lq = lane >> 4;

    floatx4 acc[4];
#pragma unroll
    for (int nb = 0; nb < 4; nb++) acc[nb] = (floatx4){0.f, 0.f, 0.f, 0.f};

    const int srow = tid >> 2;
    const int scol = (tid & 3) << 3;
    const int agrow = m0 + srow;
    const bool aok = agrow < M;
    const bf16* Aptr = A + (size_t)agrow * K + scol;
    const bf16* Bptr = WT + (size_t)(n0 + srow) * K + scol;

    for (int k0 = 0; k0 < K; k0 += 32) {
        __syncthreads();
        int4 av = make_int4(0, 0, 0, 0);
        if (aok) av = *(const int4*)(Aptr + k0);
        *(int4*)(&As[srow * 32 + scol]) = av;
        *(int4*)(&Bs[srow * 32 + scol]) = *(const int4*)(Bptr + k0);
        __syncthreads();
        short8 a = *(const short8*)(&As[(w * 16 + lm) * 32 + lq * 8]);
#pragma unroll
        for (int nb = 0; nb < 4; nb++) {
            short8 b = *(const short8*)(&Bs[(nb * 16 + lm) * 32 + lq * 8]);
            acc[nb] = __builtin_amdgcn_mfma_f32_16x16x32_bf16(a, b, acc[nb], 0, 0, 0);
        }
    }

#pragma unroll
    for (int nb = 0; nb < 4; nb++) {
        int col = n0 + nb * 16 + lm;
        float bv = bias ? bf2f(bias[col]) : 0.f;
#pragma unroll
        for (int r = 0; r < 4; r++) {
            int row = m0 + w * 16 + lq * 4 + r;
            if (row < M) {
                float v = acc[nb][r] + bv;
                if (MODE == 1) v = fast_gelu(v);
                if (MODE == 2) {
                    ((float*)outp)[(size_t)row * Nc + col] += v;
                } else {
                    ((bf16*)outp)[(size_t)row * Nc + col] = f2bf(v);
                }
            }
        }
    }
}

// ---------------------------------------------------------------------------
// 128-tile GEMM, BK=64, conflict-free k-major LDS chunks, transposed
// accumulation (weights on MFMA A-side) for a vectorizable epilogue.
// LDS layout per matrix: 8 rowblocks of 16 rows; rowblock rb stores element
// (row=rb*16+r, kchunk kc[0..7]) at [rb*1024 + kc*128 + r*8] shorts. Staged by
// global_load_lds: chunk ch (1KB) = (rb=ch>>1, half=ch&1); lane i fetches
// global row rb*16+(i&15), k-offset (half*4+(i>>4))*8 -> lands exactly there.
// Fragment reads are stride-16B across lm -> 0 bank conflicts for b128.
// MODE 0: bf16 store (LDS-staged); MODE 1: fast_gelu+bf16; MODE 2: fp32 +=.
// REQUIRES M%128==0, Nc%128==0, K%64==0.
template <int MODE>
__global__ __launch_bounds__(256) void gemm128(
    const bf16* __restrict__ A, const bf16* __restrict__ WT,
    const bf16* __restrict__ bias, void* __restrict__ outp,
    int K, int Nc)
{
    __shared__ short As[128 * 64];
    __shared__ short Bs[128 * 64];
    const int tid = threadIdx.x;
    const int m0 = blockIdx.y * 128;
    const int n0 = blockIdx.x * 128;
    const int w = tid >> 6, lane = tid & 63;
    const int lm = lane & 15, lq = lane >> 4;
    const int wy = w >> 1, wx = w & 1;  // wy: row half, wx: col half

    floatx4 acc[4][4];
#pragma unroll
    for (int cb = 0; cb < 4; cb++)
#pragma unroll
        for (int rb = 0; rb < 4; rb++) acc[cb][rb] = (floatx4){0.f, 0.f, 0.f, 0.f};

    // staging setup: wave w owns chunks w*4 .. w*4+3 of each matrix
    const bf16* gA[4];
    const bf16* gB[4];
    short* lA[4];
    short* lB[4];
#pragma unroll
    for (int j = 0; j < 4; j++) {
        int ch = w * 4 + j;
        int rb = ch >> 1;
        int kc = ((ch & 1) << 2) + (lane >> 4);
        int r = lane & 15;
        gA[j] = A + (size_t)(m0 + rb * 16 + r) * K + kc * 8;
        gB[j] = WT + (size_t)(n0 + rb * 16 + r) * K + kc * 8;
        lA[j] = &As[ch * 512];
        lB[j] = &Bs[ch * 512];
    }

    for (int k0 = 0; k0 < K; k0 += 64) {
#pragma unroll
        for (int j = 0; j < 4; j++) gl_lds16(gA[j] + k0, lA[j]);
#pragma unroll
        for (int j = 0; j < 4; j++) gl_lds16(gB[j] + k0, lB[j]);
        __syncthreads();
#pragma unroll
        for (int ks = 0; ks < 2; ks++) {
            short8 wf[4], xf[4];
#pragma unroll
            for (int cb = 0; cb < 4; cb++)
                wf[cb] = *(const short8*)(&Bs[(wx * 4 + cb) * 1024 + (ks * 4 + lq) * 128 + lm * 8]);
#pragma unroll
            for (int rb = 0; rb < 4; rb++)
                xf[rb] = *(const short8*)(&As[(wy * 4 + rb) * 1024 + (ks * 4 + lq) * 128 + lm * 8]);
#pragma unroll
            for (int cb = 0; cb < 4; cb++)
#pragma unroll
                for (int rb = 0; rb < 4; rb++)
                    acc[cb][rb] = __builtin_amdgcn_mfma_f32_16x16x32_bf16(wf[cb], xf[rb], acc[cb][rb], 0, 0, 0);
        }
        __syncthreads();
    }

    // D: out col = n0+wx*64+cb*16+lq*4+r, out row = m0+wy*64+rb*16+lm
    float4 bias4[4];
#pragma unroll
    for (int cb = 0; cb < 4; cb++) {
        if (bias) {
            const bf16* bp = bias + n0 + wx * 64 + cb * 16 + lq * 4;
            bias4[cb] = make_float4(bf2f(bp[0]), bf2f(bp[1]), bf2f(bp[2]), bf2f(bp[3]));
        } else {
            bias4[cb] = make_float4(0.f, 0.f, 0.f, 0.f);
        }
    }

    if (MODE == 2) {
        float* po = (float*)outp;
#pragma unroll
        for (int rb = 0; rb < 4; rb++) {
            size_t m = m0 + wy * 64 + rb * 16 + lm;
#pragma unroll
            for (int cb = 0; cb < 4; cb++) {
                float* p = po + m * Nc + n0 + wx * 64 + cb * 16 + lq * 4;
                float4 f = *(float4*)p;
                f.x += acc[cb][rb][0] + bias4[cb].x;
                f.y += acc[cb][rb][1] + bias4[cb].y;
                f.z += acc[cb][rb][2] + bias4[cb].z;
                f.w += acc[cb][rb][3] + bias4[cb].w;
                *(float4*)p = f;
            }
        }
    } else {
        // per-wave LDS staging (reuse As after final barrier): 16 rows x 64 cols
        unsigned short* stg = (unsigned short*)&As[w * 1024];
        unsigned short* op = (unsigned short*)outp;
#pragma unroll
        for (int rb = 0; rb < 4; rb++) {
#pragma unroll
            for (int cb = 0; cb < 4; cb++) {
                short4v pk;
#pragma unroll
                for (int r = 0; r < 4; r++) {
                    float vv = acc[cb][rb][r] + ((const float*)&bias4[cb])[r];
                    if (MODE == 1) vv = fast_gelu(vv);
                    pk[r] = (short)f2bfbits(vv);
                }
                int chunk = (cb * 2 + (lq >> 1)) ^ (lm & 7);
                *(short4v*)(&stg[lm * 64 + chunk * 8 + (lq & 1) * 4]) = pk;
            }
#pragma unroll
            for (int p = 0; p < 2; p++) {
                int row = p * 8 + (lane >> 3);
                int chunk = lane & 7;
                short8 ov = *(const short8*)(&stg[row * 64 + ((chunk ^ (row & 7)) * 8)]);
                size_t m = m0 + wy * 64 + rb * 16 + row;
                *(short8*)(op + m * Nc + n0 + wx * 64 + chunk * 8) = ov;
            }
        }
    }
}

// ---------------------------------------------------------------------------
// MFMA attention. Block = one (b,h) x 64-query tile; 4 waves, 16 q each.
template <int SPAD, int SVALID>
__global__ __launch_bounds__(256) void attn_mfma_kernel(
    const bf16* __restrict__ q, const bf16* __restrict__ k, const bf16* __restrict__ v,
    bf16* __restrict__ o, int N)
{
    constexpr int MB = SPAD / 16;   // score m-blocks over s
    constexpr int KS = SPAD / 32;   // PV k-steps over s
    __shared__ unsigned short lds[SPAD * 64 + 64 * SPAD];
    unsigned short* Ks = lds;                 // [s][64], chunk-swizzled by s&7
    unsigned short* Vt = lds + SPAD * 64;     // [d][SPAD], chunk-swizzled by d&7
    unsigned short* Pw = lds;                 // alias (after barrier)

    const int tid = threadIdx.x;
    const int b = blockIdx.x >> 3;
    const int h = blockIdx.x & 7;
    const int n0 = blockIdx.y * 64;
    const int w = tid >> 6, lane = tid & 63;
    const int lm = lane & 15, lq = lane >> 4;

    const unsigned short* kp = (const unsigned short*)k;
    const unsigned short* vp = (const unsigned short*)v;
    for (int idx = tid * 8; idx < SPAD * 64; idx += 2048) {
        int s = idx >> 6, d0 = idx & 63;
        short8 kv = {0, 0, 0, 0, 0, 0, 0, 0};
        short8 vv = {0, 0, 0, 0, 0, 0, 0, 0};
        if (s < SVALID) {
            size_t gb = ((size_t)(b * SVALID + s)) * 512 + h * 64 + d0;
            kv = *(const short8*)(kp + gb);
            vv = *(const short8*)(vp + gb);
        }
        int kc = (d0 >> 3) ^ (s & 7);
        *(short8*)(&Ks[s * 64 + kc * 8]) = kv;
        const unsigned short* vvp = (const unsigned short*)&vv;
#pragma unroll
        for (int i = 0; i < 8; i++) {
            int d = d0 + i;
            int sc = (s >> 3) ^ (d & 7);
            Vt[d * SPAD + sc * 8 + (s & 7)] = vvp[i];
        }
    }

    const int q0 = n0 + w * 16;
    const unsigned short* qp = (const unsigned short*)q;
    size_t qbase = ((size_t)(b * N + q0 + lm)) * 512 + h * 64 + lq * 8;
    short8 qf0 = *(const short8*)(qp + qbase);
    short8 qf1 = *(const short8*)(qp + qbase + 32);
    __syncthreads();

    floatx4 sacc[MB];
#pragma unroll
    for (int mb = 0; mb < MB; mb++) sacc[mb] = (floatx4){0.f, 0.f, 0.f, 0.f};
#pragma unroll
    for (int mb = 0; mb < MB; mb++) {
        int srow = mb * 16 + lm;
        short8 a0 = *(const short8*)(&Ks[srow * 64 + ((lq ^ (lm & 7)) * 8)]);
        short8 a1 = *(const short8*)(&Ks[srow * 64 + (((4 + lq) ^ (lm & 7)) * 8)]);
        sacc[mb] = __builtin_amdgcn_mfma_f32_16x16x32_bf16(a0, qf0, sacc[mb], 0, 0, 0);
        sacc[mb] = __builtin_amdgcn_mfma_f32_16x16x32_bf16(a1, qf1, sacc[mb], 0, 0, 0);
    }

    float mx = -1e30f;
#pragma unroll
    for (int mb = 0; mb < MB; mb++)
#pragma unroll
        for (int r = 0; r < 4; r++) {
            int s = mb * 16 + lq * 4 + r;
            if (s < SVALID) mx = fmaxf(mx, sacc[mb][r]);
        }
    mx = fmaxf(mx, __shfl_xor(mx, 16, 64));
    mx = fmaxf(mx, __shfl_xor(mx, 32, 64));
    mx *= 0.125f;
    float sum = 0.f;
#pragma unroll
    for (int mb = 0; mb < MB; mb++)
#pragma unroll
        for (int r = 0; r < 4; r++) {
            int s = mb * 16 + lq * 4 + r;
            float e = (s < SVALID) ? __expf(sacc[mb][r] * 0.125f - mx) : 0.f;
            sacc[mb][r] = e;
            sum += e;
        }
    sum += __shfl_xor(sum, 16, 64);
    sum += __shfl_xor(sum, 32, 64);
    float inv = 1.f / sum;

    __syncthreads();

    unsigned short* Pme = Pw + w * 16 * SPAD;
#pragma unroll
    for (int mb = 0; mb < MB; mb++) {
        short4v pk;
        pk[0] = (short)f2bfbits(sacc[mb][0] * inv);
        pk[1] = (short)f2bfbits(sacc[mb][1] * inv);
        pk[2] = (short)f2bfbits(sacc[mb][2] * inv);
        pk[3] = (short)f2bfbits(sacc[mb][3] * inv);
        int chunk = (mb * 2 + (lq >> 1)) ^ (lm & 7);
        *(short4v*)(&Pme[lm * SPAD + chunk * 8 + (lq & 1) * 4]) = pk;
    }

    floatx4 oacc[4];
#pragma unroll
    for (int mb2 = 0; mb2 < 4; mb2++) oacc[mb2] = (floatx4){0.f, 0.f, 0.f, 0.f};
    for (int ks = 0; ks < KS; ks++) {
        int sch = ((ks * 4 + lq) ^ (lm & 7)) * 8;
        short8 bfrag = *(const short8*)(&Pme[lm * SPAD + sch]);
#pragma unroll
        for (int mb2 = 0; mb2 < 4; mb2++) {
            int d = mb2 * 16 + lm;
            short8 afrag = *(const short8*)(&Vt[d * SPAD + sch]);
            oacc[mb2] = __builtin_amdgcn_mfma_f32_16x16x32_bf16(afrag, bfrag, oacc[mb2], 0, 0, 0);
        }
    }

#pragma unroll
    for (int mb2 = 0; mb2 < 4; mb2++) {
        short4v ok;
        ok[0] = (short)f2bfbits(oacc[mb2][0]);
        ok[1] = (short)f2bfbits(oacc[mb2][1]);
        ok[2] = (short)f2bfbits(oacc[mb2][2]);
        ok[3] = (short)f2bfbits(oacc[mb2][3]);
        int chunk = (mb2 * 2 + (lq >> 1)) ^ (lm & 7);
        *(short4v*)(&Pme[lm * 64 + chunk * 8 + (lq & 1) * 4]) = ok;
    }
    unsigned short* op = (unsigned short*)o;
#pragma unroll
    for (int p = 0; p < 2; p++) {
        int row = p * 8 + (lane >> 3);
        int chunk = lane & 7;
        short8 ov = *(const short8*)(&Pme[row * 64 + ((chunk ^ (row & 7)) * 8)]);
        *(short8*)(op + ((size_t)(b * N + n0 + w * 16 + row)) * 512 + h * 64 + chunk * 8) = ov;
    }
}

// ---------------------------------------------------------------------------
extern "C" void kernel_launch(void* const* d_in, const int* in_sizes, int n_in,
                              void* d_out, int out_size, void* d_ws, size_t ws_size,
                              hipStream_t stream)
{
    const void* x   = d_in[0];
    const void* ctx = d_in[1];
    const void* geo = d_in[2];
    const void* g1 = d_in[3];  const void* b1 = d_in[4];
    const void* g2 = d_in[5];  const void* b2 = d_in[6];
    const void* g3 = d_in[7];  const void* b3 = d_in[8];
    const void* g4 = d_in[9];  const void* b4 = d_in[10];
    const void* cWq = d_in[11]; const void* cWk = d_in[12];
    const void* cWv = d_in[13]; const void* cWo = d_in[14];
    const void* cbo = d_in[15];
    const void* gWq = d_in[16]; const void* gWk = d_in[17];
    const void* gWv = d_in[18]; const void* gWo = d_in[19];
    const void* gbo = d_in[20];
    const void* W1 = d_in[21];  const void* bf1 = d_in[22];
    const void* W2 = d_in[23];  const void* bf2 = d_in[24];

    const int B = 4, C = 512, NN = 4096;
    const int M = B * NN;  // 16384 token rows

    char* ws = (char*)d_ws;
    size_t off = 0;
    auto alloc = [&](size_t bytes) -> void* {
        void* p = ws + off; off += (bytes + 255) & ~(size_t)255; return p;
    };
    int*   flag = (int*)alloc(256);
    float* t  = (float*)alloc((size_t)M * C * 4);        // fp32 residual stream
    bf16* u   = (bf16*)alloc((size_t)M * C * 2);         // LN out; ob aliases u
    bf16* qb  = (bf16*)alloc((size_t)M * C * 2);         // Q
    bf16* kb  = (bf16*)alloc((size_t)B * 256 * C * 2);
    bf16* vb  = (bf16*)alloc((size_t)B * 256 * C * 2);
    bf16* ctxb = (bf16*)alloc((size_t)B * 77 * 768 * 2);
    bf16* geob = (bf16*)alloc((size_t)B * 256 * 512 * 2);
    bf16* cWqT = (bf16*)alloc((size_t)512 * 512 * 2);
    bf16* cWkT = (bf16*)alloc((size_t)512 * 768 * 2);
    bf16* cWvT = (bf16*)alloc((size_t)512 * 768 * 2);
    bf16* cWoT = (bf16*)alloc((size_t)512 * 512 * 2);
    bf16* gWqT = (bf16*)alloc((size_t)512 * 512 * 2);
    bf16* gWkT = (bf16*)alloc((size_t)512 * 512 * 2);
    bf16* gWvT = (bf16*)alloc((size_t)512 * 512 * 2);
    bf16* gWoT = (bf16*)alloc((size_t)512 * 512 * 2);
    bf16* W1T  = (bf16*)alloc((size_t)2048 * 512 * 2);
    bf16* W2T  = (bf16*)alloc((size_t)512 * 2048 * 2);
    bf16* prm  = (bf16*)alloc((size_t)7680 * 2);
    bf16* ob = u;   // attention output aliases u (u dead after Q projection)

    // FFN hidden buffer: pick largest chunking the workspace allows
    int chunk;
    bf16* hb;
    size_t rem = (ws_size > off) ? (ws_size - off) : 0;
    if (rem >= (size_t)16384 * 2048 * 2) { chunk = 16384; hb = (bf16*)alloc((size_t)16384 * 2048 * 2); }
    else if (rem >= (size_t)8192 * 2048 * 2) { chunk = 8192; hb = (bf16*)alloc((size_t)8192 * 2048 * 2); }
    else { chunk = 4096; hb = qb; }  // alias qb (dead after attention)
    (void)in_sizes; (void)n_in; (void)out_size;

    // param block layout (bf16)
    bf16 *pg1 = prm, *pb1 = prm + 512, *pg2 = prm + 1024, *pb2 = prm + 1536;
    bf16 *pg3 = prm + 2048, *pb3 = prm + 2560, *pg4 = prm + 3072, *pb4 = prm + 3584;
    bf16 *pcbo = prm + 4096, *pgbo = prm + 4608, *pbf1 = prm + 5120, *pbf2 = prm + 7168;

    dim3 tb(32, 8);

    // dtype detection + input canonicalization
    detect_kernel<<<1, 256, 0, stream>>>(x, flag);
    SegTab tab;
    const void* srcs[12] = {g1, b1, g2, b2, g3, b3, g4, b4, cbo, gbo, bf1, bf2};
    int offs[12] = {0, 512, 1024, 1536, 2048, 2560, 3072, 3584, 4096, 4608, 5120, 7168};
    int cnts[12] = {512, 512, 512, 512, 512, 512, 512, 512, 512, 512, 2048, 512};
    for (int i = 0; i < 12; i++) { tab.src[i] = srcs[i]; tab.off[i] = offs[i]; tab.cnt[i] = cnts[i]; }
    param_convert_kernel<<<12, 256, 0, stream>>>(tab, prm, flag);
    convert_kernel<<<(B * 77 * 768 + 255) / 256, 256, 0, stream>>>(ctx, ctxb, flag, B * 77 * 768);
    convert_kernel<<<(B * 256 * 512 + 255) / 256, 256, 0, stream>>>(geo, geob, flag, B * 256 * 512);

    // fused: t = transpose(x) + LN1
    ln_in_kernel<<<dim3(NN / 16, B), 256, 0, stream>>>(x, t, pg1, pb1, flag, NN);

    // weight transposes (W is KxN row-major -> WT NxK bf16)
    transpose_w_kernel<<<dim3(512 / 32, 512 / 32), tb, 0, stream>>>(cWq, cWqT, flag, 512, 512);
    transpose_w_kernel<<<dim3(512 / 32, 768 / 32), tb, 0, stream>>>(cWk, cWkT, flag, 768, 512);
    transpose_w_kernel<<<dim3(512 / 32, 768 / 32), tb, 0, stream>>>(cWv, cWvT, flag, 768, 512);
    transpose_w_kernel<<<dim3(512 / 32, 512 / 32), tb, 0, stream>>>(cWo, cWoT, flag, 512, 512);
    transpose_w_kernel<<<dim3(512 / 32, 512 / 32), tb, 0, stream>>>(gWq, gWqT, flag, 512, 512);
    transpose_w_kernel<<<dim3(512 / 32, 512 / 32), tb, 0, stream>>>(gWk, gWkT, flag, 512, 512);
    transpose_w_kernel<<<dim3(512 / 32, 512 / 32), tb, 0, stream>>>(gWv, gWvT, flag, 512, 512);
    transpose_w_kernel<<<dim3(512 / 32, 512 / 32), tb, 0, stream>>>(gWo, gWoT, flag, 512, 512);
    transpose_w_kernel<<<dim3(2048 / 32, 512 / 32), tb, 0, stream>>>(W1, W1T, flag, 512, 2048);
    transpose_w_kernel<<<dim3(512 / 32, 2048 / 32), tb, 0, stream>>>(W2, W2T, flag, 2048, 512);

    // ---- context cross-attention ----
    ln_kernel<<<M / 4, 256, 0, stream>>>(t, pg2, pb2, u, M);
    gemm128<0><<<dim3(4, M / 128), 256, 0, stream>>>(u, cWqT, nullptr, qb, 512, 512);
    gemm64<0><<<dim3(8, (308 + 63) / 64), 256, 0, stream>>>(ctxb, cWkT, nullptr, kb, 308, 768, 512);
    gemm64<0><<<dim3(8, (308 + 63) / 64), 256, 0, stream>>>(ctxb, cWvT, nullptr, vb, 308, 768, 512);
    attn_mfma_kernel<128, 77><<<dim3(B * 8, NN / 64), 256, 0, stream>>>(qb, kb, vb, ob, NN);
    gemm128<2><<<dim3(4, M / 128), 256, 0, stream>>>(ob, cWoT, pcbo, t, 512, 512);

    // ---- geometry cross-attention ----
    ln_kernel<<<M / 4, 256, 0, stream>>>(t, pg3, pb3, u, M);
    gemm128<0><<<dim3(4, M / 128), 256, 0, stream>>>(u, gWqT, nullptr, qb, 512, 512);
    gemm64<0><<<dim3(8, 1024 / 64), 256, 0, stream>>>(geob, gWkT, nullptr, kb, 1024, 512, 512);
    gemm64<0><<<dim3(8, 1024 / 64), 256, 0, stream>>>(geob, gWvT, nullptr, vb, 1024, 512, 512);
    attn_mfma_kernel<256, 256><<<dim3(B * 8, NN / 64), 256, 0, stream>>>(qb, kb, vb, ob, NN);
    gemm128<2><<<dim3(4, M / 128), 256, 0, stream>>>(ob, gWoT, pgbo, t, 512, 512);

    // ---- FFN (ws-adaptive chunking) ----
    ln_kernel<<<M / 4, 256, 0, stream>>>(t, pg4, pb4, u, M);
    for (int mc = 0; mc < M / chunk; mc++) {
        bf16* uc = u + (size_t)mc * chunk * 512;
        float* tc = t + (size_t)mc * chunk * 512;
        gemm128<1><<<dim3(2048 / 128, chunk / 128), 256, 0, stream>>>(uc, W1T, pbf1, hb, 512, 2048);
        gemm128<2><<<dim3(512 / 128, chunk / 128), 256, 0, stream>>>(hb, W2T, pbf2, tc, 2048, 512);
    }

    // out = transpose(t) in detected dtype
    transpose_out_kernel<<<dim3(NN / 32, C / 32, B), tb, 0, stream>>>(t, d_out, flag, C, NN);
}

// Round 8
// 543.920 us; speedup vs baseline: 1.0735x; 1.0735x over previous
//
#include <hip/hip_runtime.h>
#include <hip/hip_bf16.h>

using bf16 = __hip_bfloat16;
typedef __attribute__((ext_vector_type(8))) short short8;
typedef __attribute__((ext_vector_type(4))) short short4v;
typedef __attribute__((ext_vector_type(4))) float floatx4;

#define DEVFN __device__ __forceinline__

DEVFN float bf2f(bf16 v) { return __bfloat162float(v); }
DEVFN bf16 f2bf(float v) { return __float2bfloat16(v); }
DEVFN float us2f(unsigned short u) {
    union { unsigned int i; float f; } c; c.i = ((unsigned int)u) << 16; return c.f;
}
DEVFN unsigned short f2bfbits(float v) {
    union { bf16 h; unsigned short u; } c; c.h = f2bf(v); return c.u;
}
// dtype-dispatched load: isf=1 -> fp32 buffer, isf=0 -> bf16 buffer
DEVFN float loadF(const void* p, size_t i, int isf) {
    return isf ? ((const float*)p)[i] : us2f(((const unsigned short*)p)[i]);
}
// async global->LDS, 16B per lane; lds dest = wave-uniform base + lane*16
DEVFN void gl_lds16(const bf16* g, short* l) {
    __builtin_amdgcn_global_load_lds(
        (const __attribute__((address_space(1))) unsigned int*)g,
        (__attribute__((address_space(3))) unsigned int*)l, 16, 0, 0);
}
// tanh-form GELU, overflow-safe
DEVFN float fast_gelu(float v) {
    float u = v * (0.7978845608028654f + 0.0356774081f * v * v);
    float e = __expf(2.f * u);
    float th = 1.f - 2.f / (e + 1.f);
    return 0.5f * v * (1.f + th);
}

// ---------------------------------------------------------------------------
// Detect input dtype: fp32 N(0,1) -> low halves random -> exp==0xFF hits.
__global__ __launch_bounds__(256) void detect_kernel(const void* x, int* flag)
{
    __shared__ int any;
    if (threadIdx.x == 0) any = 0;
    __syncthreads();
    const unsigned short* p = (const unsigned short*)x;
    int hit = 0;
    for (int i = threadIdx.x; i < 8192; i += 256) {
        if ((p[i] & 0x7F80u) == 0x7F80u) hit = 1;
    }
    if (hit) any = 1;
    __syncthreads();
    if (threadIdx.x == 0) flag[0] = any;
}

__global__ __launch_bounds__(256) void convert_kernel(
    const void* __restrict__ src, bf16* __restrict__ dst, const int* __restrict__ flag, int n)
{
    int isf = *flag;
    int i = blockIdx.x * 256 + threadIdx.x;
    if (i < n) dst[i] = f2bf(loadF(src, i, isf));
}

struct SegTab {
    const void* src[12];
    int off[12];
    int cnt[12];
};
__global__ __launch_bounds__(256) void param_convert_kernel(
    SegTab tab, bf16* __restrict__ dst, const int* __restrict__ flag)
{
    int isf = *flag;
    int s = blockIdx.x;
    const void* src = tab.src[s];
    int off = tab.off[s], cnt = tab.cnt[s];
    for (int i = threadIdx.x; i < cnt; i += 256)
        dst[off + i] = f2bf(loadF(src, i, isf));
}

// ---------------------------------------------------------------------------
// Fused: t[b,n,:] = x[b,:,n] (transpose) then t += LN1(t), all in one pass.
__global__ __launch_bounds__(256) void ln_in_kernel(
    const void* __restrict__ x, float* __restrict__ t,
    const bf16* __restrict__ g, const bf16* __restrict__ bta,
    const int* __restrict__ flag, int NN)
{
    __shared__ float tile[16][516];
    int isf = *flag;
    int b = blockIdx.y;
    int n0 = blockIdx.x * 16;
    int tid = threadIdx.x;
    int nx = tid & 15, cy = tid >> 4;
#pragma unroll
    for (int p = 0; p < 32; p++) {
        int c = p * 16 + cy;
        tile[nx][c] = loadF(x, ((size_t)b * 512 + c) * NN + n0 + nx, isf);
    }
    __syncthreads();
    int w = tid >> 6, lane = tid & 63;
    for (int rr = 0; rr < 4; rr++) {
        int r = w * 4 + rr;
        float4 v0 = *(const float4*)&tile[r][lane * 8];
        float4 v1 = *(const float4*)&tile[r][lane * 8 + 4];
        float vals[8] = {v0.x, v0.y, v0.z, v0.w, v1.x, v1.y, v1.z, v1.w};
        float s = 0.f;
#pragma unroll
        for (int i = 0; i < 8; i++) s += vals[i];
#pragma unroll
        for (int off = 32; off; off >>= 1) s += __shfl_xor(s, off, 64);
        float mu = s * (1.f / 512.f);
        float sq = 0.f;
#pragma unroll
        for (int i = 0; i < 8; i++) { float d = vals[i] - mu; sq += d * d; }
#pragma unroll
        for (int off = 32; off; off >>= 1) sq += __shfl_xor(sq, off, 64);
        float rs = rsqrtf(sq * (1.f / 512.f) + 1e-5f);
        float out[8];
#pragma unroll
        for (int i = 0; i < 8; i++) {
            int c = lane * 8 + i;
            out[i] = vals[i] + (vals[i] - mu) * rs * bf2f(g[c]) + bf2f(bta[c]);
        }
        float* tp = t + ((size_t)b * NN + n0 + r) * 512 + lane * 8;
        *(float4*)tp = make_float4(out[0], out[1], out[2], out[3]);
        *(float4*)(tp + 4) = make_float4(out[4], out[5], out[6], out[7]);
    }
}

// Transpose t (B,N,C) fp32 -> out (B,C,N) in the detected output dtype
__global__ __launch_bounds__(256) void transpose_out_kernel(
    const float* __restrict__ t, void* __restrict__ o, const int* __restrict__ flag,
    int C, int NN)
{
    __shared__ float tile[32][33];
    int isf = *flag;
    int b = blockIdx.z;
    int n0 = blockIdx.x * 32, c0 = blockIdx.y * 32;
    int tx = threadIdx.x, ty = threadIdx.y;
#pragma unroll
    for (int i = 0; i < 4; i++)
        tile[ty + i * 8][tx] = t[((size_t)b * NN + n0 + ty + i * 8) * C + c0 + tx];
    __syncthreads();
#pragma unroll
    for (int i = 0; i < 4; i++) {
        size_t oi = ((size_t)b * C + c0 + ty + i * 8) * NN + n0 + tx;
        float val = tile[tx][ty + i * 8];
        if (isf) ((float*)o)[oi] = val;
        else ((bf16*)o)[oi] = f2bf(val);
    }
}

// Transpose W (K,Nc) -> WT (Nc,K) bf16
__global__ __launch_bounds__(256) void transpose_w_kernel(
    const void* __restrict__ Wm, bf16* __restrict__ WT, const int* __restrict__ flag,
    int K, int Nc)
{
    __shared__ float tile[32][33];
    int isf = *flag;
    int n0 = blockIdx.x * 32, k0 = blockIdx.y * 32;
    int tx = threadIdx.x, ty = threadIdx.y;
#pragma unroll
    for (int i = 0; i < 4; i++)
        tile[ty + i * 8][tx] = loadF(Wm, (size_t)(k0 + ty + i * 8) * Nc + n0 + tx, isf);
    __syncthreads();
#pragma unroll
    for (int i = 0; i < 4; i++)
        WT[(size_t)(n0 + ty + i * 8) * K + k0 + tx] = f2bf(tile[tx][ty + i * 8]);
}

// ---------------------------------------------------------------------------
// LayerNorm over C=512: out = bf16(LN(t)).
__global__ __launch_bounds__(256) void ln_kernel(
    const float* __restrict__ t, const bf16* __restrict__ g, const bf16* __restrict__ bta,
    bf16* __restrict__ outp, int Mrows)
{
    int w = threadIdx.x >> 6, lane = threadIdx.x & 63;
    int row = blockIdx.x * 4 + w;
    if (row >= Mrows) return;
    const float* xr = t + (size_t)row * 512;
    float4 v0 = *(const float4*)(xr + lane * 8);
    float4 v1 = *(const float4*)(xr + lane * 8 + 4);
    float vals[8] = {v0.x, v0.y, v0.z, v0.w, v1.x, v1.y, v1.z, v1.w};
    float s = 0.f;
#pragma unroll
    for (int i = 0; i < 8; i++) s += vals[i];
#pragma unroll
    for (int off = 32; off; off >>= 1) s += __shfl_xor(s, off, 64);
    float mu = s * (1.f / 512.f);
    float sq = 0.f;
#pragma unroll
    for (int i = 0; i < 8; i++) { float d = vals[i] - mu; sq += d * d; }
#pragma unroll
    for (int off = 32; off; off >>= 1) sq += __shfl_xor(sq, off, 64);
    float rs = rsqrtf(sq * (1.f / 512.f) + 1e-5f);
#pragma unroll
    for (int i = 0; i < 8; i++) {
        int c = lane * 8 + i;
        float y = (vals[i] - mu) * rs * bf2f(g[c]) + bf2f(bta[c]);
        outp[(size_t)row * 512 + c] = f2bf(y);
    }
}

// ---------------------------------------------------------------------------
// 64-tile GEMM (kept for small/ragged M): out = epi(A @ WT^T + bias)
template <int MODE>
__global__ __launch_bounds__(256) void gemm64(
    const bf16* __restrict__ A, const bf16* __restrict__ WT,
    const bf16* __restrict__ bias, void* __restrict__ outp,
    int M, int K, int Nc)
{
    __shared__ short As[64 * 32];
    __shared__ short Bs[64 * 32];
    const int tid = threadIdx.x;
    const int m0 = blockIdx.y * 64;
    const int n0 = blockIdx.x * 64;
    const int w = tid >> 6;
    const int lane = tid & 63;
    const int lm = lane & 15;
    const int lq = lane >> 4;

    floatx4 acc[4];
#pragma unroll
    for (int nb = 0; nb < 4; nb++) acc[nb] = (floatx4){0.f, 0.f, 0.f, 0.f};

    const int srow = tid >> 2;
    const int scol = (tid & 3) << 3;
    const int agrow = m0 + srow;
    const bool aok = agrow < M;
    const bf16* Aptr = A + (size_t)agrow * K + scol;
    const bf16* Bptr = WT + (size_t)(n0 + srow) * K + scol;

    for (int k0 = 0; k0 < K; k0 += 32) {
        __syncthreads();
        int4 av = make_int4(0, 0, 0, 0);
        if (aok) av = *(const int4*)(Aptr + k0);
        *(int4*)(&As[srow * 32 + scol]) = av;
        *(int4*)(&Bs[srow * 32 + scol]) = *(const int4*)(Bptr + k0);
        __syncthreads();
        short8 a = *(const short8*)(&As[(w * 16 + lm) * 32 + lq * 8]);
#pragma unroll
        for (int nb = 0; nb < 4; nb++) {
            short8 b = *(const short8*)(&Bs[(nb * 16 + lm) * 32 + lq * 8]);
            acc[nb] = __builtin_amdgcn_mfma_f32_16x16x32_bf16(a, b, acc[nb], 0, 0, 0);
        }
    }

#pragma unroll
    for (int nb = 0; nb < 4; nb++) {
        int col = n0 + nb * 16 + lm;
        float bv = bias ? bf2f(bias[col]) : 0.f;
#pragma unroll
        for (int r = 0; r < 4; r++) {
            int row = m0 + w * 16 + lq * 4 + r;
            if (row < M) {
                float v = acc[nb][r] + bv;
                if (MODE == 1) v = fast_gelu(v);
                if (MODE == 2) {
                    ((float*)outp)[(size_t)row * Nc + col] += v;
                } else {
                    ((bf16*)outp)[(size_t)row * Nc + col] = f2bf(v);
                }
            }
        }
    }
}

// ---------------------------------------------------------------------------
// 128-tile GEMM, BK=32 (round-6 structure) + global-side XOR swizzle:
// staging lane i -> row lr=i>>2, LDS slot j=i&3, but fetches global k-chunk
// (j ^ (lr&3)) -> each 4-lane group still fetches the same contiguous 64B
// (coalescing identical to round 6), while LDS slot (row, j) holds kc =
// j^(row&3), so fragment reads at [row*32 + (lq^(row&3))*8] cover every 16B
// block exactly once -> bank-even (conflict-free) ds_read_b128.
// Transposed accumulation (weights on MFMA A-side) for vectorizable epilogue.
// MODE 0: bf16 store (LDS-staged); MODE 1: fast_gelu+bf16; MODE 2: fp32 +=.
// REQUIRES M%128==0, Nc%128==0, K%32==0.
template <int MODE>
__global__ __launch_bounds__(256) void gemm128(
    const bf16* __restrict__ A, const bf16* __restrict__ WT,
    const bf16* __restrict__ bias, void* __restrict__ outp,
    int K, int Nc)
{
    __shared__ short As[128 * 32];
    __shared__ short Bs[128 * 32];
    const int tid = threadIdx.x;
    const int m0 = blockIdx.y * 128;
    const int n0 = blockIdx.x * 128;
    const int w = tid >> 6, lane = tid & 63;
    const int lm = lane & 15, lq = lane >> 4;
    const int wy = w >> 1, wx = w & 1;  // wy: row half, wx: col half

    floatx4 acc[4][4];
#pragma unroll
    for (int cb = 0; cb < 4; cb++)
#pragma unroll
        for (int rb = 0; rb < 4; rb++) acc[cb][rb] = (floatx4){0.f, 0.f, 0.f, 0.f};

    // staging: wave w owns chunks w*2, w*2+1 (each 16 rows x 32 shorts)
    const int c0 = w * 2, c1 = w * 2 + 1;
    const int lr = lane >> 2;
    const int lk = (((lane & 3) ^ (lr & 3)) << 3);   // XOR-swizzled global k-chunk
    const bf16* gA0 = A + (size_t)(m0 + c0 * 16 + lr) * K + lk;
    const bf16* gA1 = A + (size_t)(m0 + c1 * 16 + lr) * K + lk;
    const bf16* gB0 = WT + (size_t)(n0 + c0 * 16 + lr) * K + lk;
    const bf16* gB1 = WT + (size_t)(n0 + c1 * 16 + lr) * K + lk;
    short* lA0 = &As[c0 * 512];
    short* lA1 = &As[c1 * 512];
    short* lB0 = &Bs[c0 * 512];
    short* lB1 = &Bs[c1 * 512];

    const int fsw = ((lq ^ (lm & 3)) * 8);   // fragment-read swizzled k-slot
    for (int k0 = 0; k0 < K; k0 += 32) {
        gl_lds16(gA0 + k0, lA0);
        gl_lds16(gA1 + k0, lA1);
        gl_lds16(gB0 + k0, lB0);
        gl_lds16(gB1 + k0, lB1);
        __syncthreads();
        short8 wf[4], xf[4];
#pragma unroll
        for (int cb = 0; cb < 4; cb++)
            wf[cb] = *(const short8*)(&Bs[(wx * 64 + cb * 16 + lm) * 32 + fsw]);
#pragma unroll
        for (int rb = 0; rb < 4; rb++)
            xf[rb] = *(const short8*)(&As[(wy * 64 + rb * 16 + lm) * 32 + fsw]);
#pragma unroll
        for (int cb = 0; cb < 4; cb++)
#pragma unroll
            for (int rb = 0; rb < 4; rb++)
                acc[cb][rb] = __builtin_amdgcn_mfma_f32_16x16x32_bf16(wf[cb], xf[rb], acc[cb][rb], 0, 0, 0);
        __syncthreads();
    }

    // D: out col = n0+wx*64+cb*16+lq*4+r, out row = m0+wy*64+rb*16+lm
    float4 bias4[4];
#pragma unroll
    for (int cb = 0; cb < 4; cb++) {
        if (bias) {
            const bf16* bp = bias + n0 + wx * 64 + cb * 16 + lq * 4;
            bias4[cb] = make_float4(bf2f(bp[0]), bf2f(bp[1]), bf2f(bp[2]), bf2f(bp[3]));
        } else {
            bias4[cb] = make_float4(0.f, 0.f, 0.f, 0.f);
        }
    }

    if (MODE == 2) {
        float* po = (float*)outp;
#pragma unroll
        for (int rb = 0; rb < 4; rb++) {
            size_t m = m0 + wy * 64 + rb * 16 + lm;
#pragma unroll
            for (int cb = 0; cb < 4; cb++) {
                float* p = po + m * Nc + n0 + wx * 64 + cb * 16 + lq * 4;
                float4 f = *(float4*)p;
                f.x += acc[cb][rb][0] + bias4[cb].x;
                f.y += acc[cb][rb][1] + bias4[cb].y;
                f.z += acc[cb][rb][2] + bias4[cb].z;
                f.w += acc[cb][rb][3] + bias4[cb].w;
                *(float4*)p = f;
            }
        }
    } else {
        // per-wave LDS staging (reuse As after final barrier): 16 rows x 64 cols
        unsigned short* stg = (unsigned short*)&As[w * 1024];
        unsigned short* op = (unsigned short*)outp;
#pragma unroll
        for (int rb = 0; rb < 4; rb++) {
#pragma unroll
            for (int cb = 0; cb < 4; cb++) {
                short4v pk;
#pragma unroll
                for (int r = 0; r < 4; r++) {
                    float vv = acc[cb][rb][r] + ((const float*)&bias4[cb])[r];
                    if (MODE == 1) vv = fast_gelu(vv);
                    pk[r] = (short)f2bfbits(vv);
                }
                int chunk = (cb * 2 + (lq >> 1)) ^ (lm & 7);
                *(short4v*)(&stg[lm * 64 + chunk * 8 + (lq & 1) * 4]) = pk;
            }
#pragma unroll
            for (int p = 0; p < 2; p++) {
                int row = p * 8 + (lane >> 3);
                int chunk = lane & 7;
                short8 ov = *(const short8*)(&stg[row * 64 + ((chunk ^ (row & 7)) * 8)]);
                size_t m = m0 + wy * 64 + rb * 16 + row;
                *(short8*)(op + m * Nc + n0 + wx * 64 + chunk * 8) = ov;
            }
        }
    }
}

// ---------------------------------------------------------------------------
// MFMA attention. Block = one (b,h) x 64-query tile; 4 waves, 16 q each.
template <int SPAD, int SVALID>
__global__ __launch_bounds__(256) void attn_mfma_kernel(
    const bf16* __restrict__ q, const bf16* __restrict__ k, const bf16* __restrict__ v,
    bf16* __restrict__ o, int N)
{
    constexpr int MB = SPAD / 16;   // score m-blocks over s
    constexpr int KS = SPAD / 32;   // PV k-steps over s
    __shared__ unsigned short lds[SPAD * 64 + 64 * SPAD];
    unsigned short* Ks = lds;                 // [s][64], chunk-swizzled by s&7
    unsigned short* Vt = lds + SPAD * 64;     // [d][SPAD], chunk-swizzled by d&7
    unsigned short* Pw = lds;                 // alias (after barrier)

    const int tid = threadIdx.x;
    const int b = blockIdx.x >> 3;
    const int h = blockIdx.x & 7;
    const int n0 = blockIdx.y * 64;
    const int w = tid >> 6, lane = tid & 63;
    const int lm = lane & 15, lq = lane >> 4;

    const unsigned short* kp = (const unsigned short*)k;
    const unsigned short* vp = (const unsigned short*)v;
    for (int idx = tid * 8; idx < SPAD * 64; idx += 2048) {
        int s = idx >> 6, d0 = idx & 63;
        short8 kv = {0, 0, 0, 0, 0, 0, 0, 0};
        short8 vv = {0, 0, 0, 0, 0, 0, 0, 0};
        if (s < SVALID) {
            size_t gb = ((size_t)(b * SVALID + s)) * 512 + h * 64 + d0;
            kv = *(const short8*)(kp + gb);
            vv = *(const short8*)(vp + gb);
        }
        int kc = (d0 >> 3) ^ (s & 7);
        *(short8*)(&Ks[s * 64 + kc * 8]) = kv;
        const unsigned short* vvp = (const unsigned short*)&vv;
#pragma unroll
        for (int i = 0; i < 8; i++) {
            int d = d0 + i;
            int sc = (s >> 3) ^ (d & 7);
            Vt[d * SPAD + sc * 8 + (s & 7)] = vvp[i];
        }
    }

    const int q0 = n0 + w * 16;
    const unsigned short* qp = (const unsigned short*)q;
    size_t qbase = ((size_t)(b * N + q0 + lm)) * 512 + h * 64 + lq * 8;
    short8 qf0 = *(const short8*)(qp + qbase);
    short8 qf1 = *(const short8*)(qp + qbase + 32);
    __syncthreads();

    floatx4 sacc[MB];
#pragma unroll
    for (int mb = 0; mb < MB; mb++) sacc[mb] = (floatx4){0.f, 0.f, 0.f, 0.f};
#pragma unroll
    for (int mb = 0; mb < MB; mb++) {
        int srow = mb * 16 + lm;
        short8 a0 = *(const short8*)(&Ks[srow * 64 + ((lq ^ (lm & 7)) * 8)]);
        short8 a1 = *(const short8*)(&Ks[srow * 64 + (((4 + lq) ^ (lm & 7)) * 8)]);
        sacc[mb] = __builtin_amdgcn_mfma_f32_16x16x32_bf16(a0, qf0, sacc[mb], 0, 0, 0);
        sacc[mb] = __builtin_amdgcn_mfma_f32_16x16x32_bf16(a1, qf1, sacc[mb], 0, 0, 0);
    }

    float mx = -1e30f;
#pragma unroll
    for (int mb = 0; mb < MB; mb++)
#pragma unroll
        for (int r = 0; r < 4; r++) {
            int s = mb * 16 + lq * 4 + r;
            if (s < SVALID) mx = fmaxf(mx, sacc[mb][r]);
        }
    mx = fmaxf(mx, __shfl_xor(mx, 16, 64));
    mx = fmaxf(mx, __shfl_xor(mx, 32, 64));
    mx *= 0.125f;
    float sum = 0.f;
#pragma unroll
    for (int mb = 0; mb < MB; mb++)
#pragma unroll
        for (int r = 0; r < 4; r++) {
            int s = mb * 16 + lq * 4 + r;
            float e = (s < SVALID) ? __expf(sacc[mb][r] * 0.125f - mx) : 0.f;
            sacc[mb][r] = e;
            sum += e;
        }
    sum += __shfl_xor(sum, 16, 64);
    sum += __shfl_xor(sum, 32, 64);
    float inv = 1.f / sum;

    __syncthreads();

    unsigned short* Pme = Pw + w * 16 * SPAD;
#pragma unroll
    for (int mb = 0; mb < MB; mb++) {
        short4v pk;
        pk[0] = (short)f2bfbits(sacc[mb][0] * inv);
        pk[1] = (short)f2bfbits(sacc[mb][1] * inv);
        pk[2] = (short)f2bfbits(sacc[mb][2] * inv);
        pk[3] = (short)f2bfbits(sacc[mb][3] * inv);
        int chunk = (mb * 2 + (lq >> 1)) ^ (lm & 7);
        *(short4v*)(&Pme[lm * SPAD + chunk * 8 + (lq & 1) * 4]) = pk;
    }

    floatx4 oacc[4];
#pragma unroll
    for (int mb2 = 0; mb2 < 4; mb2++) oacc[mb2] = (floatx4){0.f, 0.f, 0.f, 0.f};
    for (int ks = 0; ks < KS; ks++) {
        int sch = ((ks * 4 + lq) ^ (lm & 7)) * 8;
        short8 bfrag = *(const short8*)(&Pme[lm * SPAD + sch]);
#pragma unroll
        for (int mb2 = 0; mb2 < 4; mb2++) {
            int d = mb2 * 16 + lm;
            short8 afrag = *(const short8*)(&Vt[d * SPAD + sch]);
            oacc[mb2] = __builtin_amdgcn_mfma_f32_16x16x32_bf16(afrag, bfrag, oacc[mb2], 0, 0, 0);
        }
    }

#pragma unroll
    for (int mb2 = 0; mb2 < 4; mb2++) {
        short4v ok;
        ok[0] = (short)f2bfbits(oacc[mb2][0]);
        ok[1] = (short)f2bfbits(oacc[mb2][1]);
        ok[2] = (short)f2bfbits(oacc[mb2][2]);
        ok[3] = (short)f2bfbits(oacc[mb2][3]);
        int chunk = (mb2 * 2 + (lq >> 1)) ^ (lm & 7);
        *(short4v*)(&Pme[lm * 64 + chunk * 8 + (lq & 1) * 4]) = ok;
    }
    unsigned short* op = (unsigned short*)o;
#pragma unroll
    for (int p = 0; p < 2; p++) {
        int row = p * 8 + (lane >> 3);
        int chunk = lane & 7;
        short8 ov = *(const short8*)(&Pme[row * 64 + ((chunk ^ (row & 7)) * 8)]);
        *(short8*)(op + ((size_t)(b * N + n0 + w * 16 + row)) * 512 + h * 64 + chunk * 8) = ov;
    }
}

// ---------------------------------------------------------------------------
extern "C" void kernel_launch(void* const* d_in, const int* in_sizes, int n_in,
                              void* d_out, int out_size, void* d_ws, size_t ws_size,
                              hipStream_t stream)
{
    const void* x   = d_in[0];
    const void* ctx = d_in[1];
    const void* geo = d_in[2];
    const void* g1 = d_in[3];  const void* b1 = d_in[4];
    const void* g2 = d_in[5];  const void* b2 = d_in[6];
    const void* g3 = d_in[7];  const void* b3 = d_in[8];
    const void* g4 = d_in[9];  const void* b4 = d_in[10];
    const void* cWq = d_in[11]; const void* cWk = d_in[12];
    const void* cWv = d_in[13]; const void* cWo = d_in[14];
    const void* cbo = d_in[15];
    const void* gWq = d_in[16]; const void* gWk = d_in[17];
    const void* gWv = d_in[18]; const void* gWo = d_in[19];
    const void* gbo = d_in[20];
    const void* W1 = d_in[21];  const void* bf1 = d_in[22];
    const void* W2 = d_in[23];  const void* bf2 = d_in[24];

    const int B = 4, C = 512, NN = 4096;
    const int M = B * NN;  // 16384 token rows

    char* ws = (char*)d_ws;
    size_t off = 0;
    auto alloc = [&](size_t bytes) -> void* {
        void* p = ws + off; off += (bytes + 255) & ~(size_t)255; return p;
    };
    int*   flag = (int*)alloc(256);
    float* t  = (float*)alloc((size_t)M * C * 4);        // fp32 residual stream
    bf16* u   = (bf16*)alloc((size_t)M * C * 2);         // LN out; ob aliases u
    bf16* qb  = (bf16*)alloc((size_t)M * C * 2);         // Q
    bf16* kb  = (bf16*)alloc((size_t)B * 256 * C * 2);
    bf16* vb  = (bf16*)alloc((size_t)B * 256 * C * 2);
    bf16* ctxb = (bf16*)alloc((size_t)B * 77 * 768 * 2);
    bf16* geob = (bf16*)alloc((size_t)B * 256 * 512 * 2);
    bf16* cWqT = (bf16*)alloc((size_t)512 * 512 * 2);
    bf16* cWkT = (bf16*)alloc((size_t)512 * 768 * 2);
    bf16* cWvT = (bf16*)alloc((size_t)512 * 768 * 2);
    bf16* cWoT = (bf16*)alloc((size_t)512 * 512 * 2);
    bf16* gWqT = (bf16*)alloc((size_t)512 * 512 * 2);
    bf16* gWkT = (bf16*)alloc((size_t)512 * 512 * 2);
    bf16* gWvT = (bf16*)alloc((size_t)512 * 512 * 2);
    bf16* gWoT = (bf16*)alloc((size_t)512 * 512 * 2);
    bf16* W1T  = (bf16*)alloc((size_t)2048 * 512 * 2);
    bf16* W2T  = (bf16*)alloc((size_t)512 * 2048 * 2);
    bf16* prm  = (bf16*)alloc((size_t)7680 * 2);
    bf16* ob = u;   // attention output aliases u (u dead after Q projection)

    // FFN hidden buffer: pick largest chunking the workspace allows
    int chunk;
    bf16* hb;
    size_t rem = (ws_size > off) ? (ws_size - off) : 0;
    if (rem >= (size_t)16384 * 2048 * 2) { chunk = 16384; hb = (bf16*)alloc((size_t)16384 * 2048 * 2); }
    else if (rem >= (size_t)8192 * 2048 * 2) { chunk = 8192; hb = (bf16*)alloc((size_t)8192 * 2048 * 2); }
    else { chunk = 4096; hb = qb; }  // alias qb (dead after attention)
    (void)in_sizes; (void)n_in; (void)out_size;

    // param block layout (bf16)
    bf16 *pg1 = prm, *pb1 = prm + 512, *pg2 = prm + 1024, *pb2 = prm + 1536;
    bf16 *pg3 = prm + 2048, *pb3 = prm + 2560, *pg4 = prm + 3072, *pb4 = prm + 3584;
    bf16 *pcbo = prm + 4096, *pgbo = prm + 4608, *pbf1 = prm + 5120, *pbf2 = prm + 7168;

    dim3 tb(32, 8);

    // dtype detection + input canonicalization
    detect_kernel<<<1, 256, 0, stream>>>(x, flag);
    SegTab tab;
    const void* srcs[12] = {g1, b1, g2, b2, g3, b3, g4, b4, cbo, gbo, bf1, bf2};
    int offs[12] = {0, 512, 1024, 1536, 2048, 2560, 3072, 3584, 4096, 4608, 5120, 7168};
    int cnts[12] = {512, 512, 512, 512, 512, 512, 512, 512, 512, 512, 2048, 512};
    for (int i = 0; i < 12; i++) { tab.src[i] = srcs[i]; tab.off[i] = offs[i]; tab.cnt[i] = cnts[i]; }
    param_convert_kernel<<<12, 256, 0, stream>>>(tab, prm, flag);
    convert_kernel<<<(B * 77 * 768 + 255) / 256, 256, 0, stream>>>(ctx, ctxb, flag, B * 77 * 768);
    convert_kernel<<<(B * 256 * 512 + 255) / 256, 256, 0, stream>>>(geo, geob, flag, B * 256 * 512);

    // fused: t = transpose(x) + LN1
    ln_in_kernel<<<dim3(NN / 16, B), 256, 0, stream>>>(x, t, pg1, pb1, flag, NN);

    // weight transposes (W is KxN row-major -> WT NxK bf16)
    transpose_w_kernel<<<dim3(512 / 32, 512 / 32), tb, 0, stream>>>(cWq, cWqT, flag, 512, 512);
    transpose_w_kernel<<<dim3(512 / 32, 768 / 32), tb, 0, stream>>>(cWk, cWkT, flag, 768, 512);
    transpose_w_kernel<<<dim3(512 / 32, 768 / 32), tb, 0, stream>>>(cWv, cWvT, flag, 768, 512);
    transpose_w_kernel<<<dim3(512 / 32, 512 / 32), tb, 0, stream>>>(cWo, cWoT, flag, 512, 512);
    transpose_w_kernel<<<dim3(512 / 32, 512 / 32), tb, 0, stream>>>(gWq, gWqT, flag, 512, 512);
    transpose_w_kernel<<<dim3(512 / 32, 512 / 32), tb, 0, stream>>>(gWk, gWkT, flag, 512, 512);
    transpose_w_kernel<<<dim3(512 / 32, 512 / 32), tb, 0, stream>>>(gWv, gWvT, flag, 512, 512);
    transpose_w_kernel<<<dim3(512 / 32, 512 / 32), tb, 0, stream>>>(gWo, gWoT, flag, 512, 512);
    transpose_w_kernel<<<dim3(2048 / 32, 512 / 32), tb, 0, stream>>>(W1, W1T, flag, 512, 2048);
    transpose_w_kernel<<<dim3(512 / 32, 2048 / 32), tb, 0, stream>>>(W2, W2T, flag, 2048, 512);

    // ---- context cross-attention ----
    ln_kernel<<<M / 4, 256, 0, stream>>>(t, pg2, pb2, u, M);
    gemm128<0><<<dim3(4, M / 128), 256, 0, stream>>>(u, cWqT, nullptr, qb, 512, 512);
    gemm64<0><<<dim3(8, (308 + 63) / 64), 256, 0, stream>>>(ctxb, cWkT, nullptr, kb, 308, 768, 512);
    gemm64<0><<<dim3(8, (308 + 63) / 64), 256, 0, stream>>>(ctxb, cWvT, nullptr, vb, 308, 768, 512);
    attn_mfma_kernel<128, 77><<<dim3(B * 8, NN / 64), 256, 0, stream>>>(qb, kb, vb, ob, NN);
    gemm128<2><<<dim3(4, M / 128), 256, 0, stream>>>(ob, cWoT, pcbo, t, 512, 512);

    // ---- geometry cross-attention ----
    ln_kernel<<<M / 4, 256, 0, stream>>>(t, pg3, pb3, u, M);
    gemm128<0><<<dim3(4, M / 128), 256, 0, stream>>>(u, gWqT, nullptr, qb, 512, 512);
    gemm64<0><<<dim3(8, 1024 / 64), 256, 0, stream>>>(geob, gWkT, nullptr, kb, 1024, 512, 512);
    gemm64<0><<<dim3(8, 1024 / 64), 256, 0, stream>>>(geob, gWvT, nullptr, vb, 1024, 512, 512);
    attn_mfma_kernel<256, 256><<<dim3(B * 8, NN / 64), 256, 0, stream>>>(qb, kb, vb, ob, NN);
    gemm128<2><<<dim3(4, M / 128), 256, 0, stream>>>(ob, gWoT, pgbo, t, 512, 512);

    // ---- FFN (ws-adaptive chunking) ----
    ln_kernel<<<M / 4, 256, 0, stream>>>(t, pg4, pb4, u, M);
    for (int mc = 0; mc < M / chunk; mc++) {
        bf16* uc = u + (size_t)mc * chunk * 512;
        float* tc = t + (size_t)mc * chunk * 512;
        gemm128<1><<<dim3(2048 / 128, chunk / 128), 256, 0, stream>>>(uc, W1T, pbf1, hb, 512, 2048);
        gemm128<2><<<dim3(512 / 128, chunk / 128), 256, 0, stream>>>(hb, W2T, pbf2, tc, 2048, 512);
    }

    // out = transpose(t) in detected dtype
    transpose_out_kernel<<<dim3(NN / 32, C / 32, B), tb, 0, stream>>>(t, d_out, flag, C, NN);
}